// Round 3
// baseline (1225.450 us; speedup 1.0000x reference)
//
#include <hip/hip_runtime.h>
#include <math.h>

// ChildSumTreeLSTM — bf16 split-precision MFMA, LDS-free version.
// A and B operands are read DIRECT global->register:
//  - W_in/W_up pre-split (hi/lo bf16) into an n-major K-tiled layout where
//    each wave's B-fragment load covers one contiguous 1KiB block (perfect
//    coalescing, L2-resident weights). No LDS, no barriers, no bank conflicts.
//  - x rows are block-private: converted fp32->hi/lo bf16 in registers.
// Gates i,o,u,f for a (parent,d) all land in the same lane's accumulators
// (wave = 16 parents x all 512 gate cols), so the LSTM elementwise + pair
// reduction is fully register-local.

#define DIN 768
#define DH  128
#define G4  512

typedef __attribute__((ext_vector_type(8))) short short8v;
typedef __attribute__((ext_vector_type(4))) float float4v;

__device__ __forceinline__ unsigned short bf16_rne(float v) {
    unsigned u = __float_as_uint(v);
    return (unsigned short)((u + 0x7FFFu + ((u >> 16) & 1u)) >> 16);
}
__device__ __forceinline__ float bf16_to_f(unsigned short h) {
    return __uint_as_float(((unsigned)h) << 16);
}
__device__ __forceinline__ void split_bf(float v, unsigned short& hi, unsigned short& lo) {
    hi = bf16_rne(v);
    lo = bf16_rne(v - bf16_to_f(hi));
}
__device__ __forceinline__ float sigf(float x) {
    return 1.0f / (1.0f + __expf(-x));
}
__device__ __forceinline__ float tanh_fast(float x) {
    // 1 - 2/(1+e^{2x}); saturates correctly for |x| large, no NaN for finite x
    return 1.0f - 2.0f / (1.0f + __expf(2.0f * x));
}

// ---------------------------------------------------------------------------
// Split W_in and W_up into hi/lo bf16, K-tiled n-major layout:
//   tile s holds k in [s*32, s*32+32); element (n, kk) at [(s*N + n)*32 + kk]
// => a wave's B-fragment (16 n-values x 4 k-chunks of 16B) is one contiguous
//    1KiB block.
// ---------------------------------------------------------------------------
__global__ __launch_bounds__(256) void split_weights(
    const float* __restrict__ Wi, const float* __restrict__ Wu,
    unsigned short* __restrict__ wi_hi, unsigned short* __restrict__ wi_lo,
    unsigned short* __restrict__ wu_hi, unsigned short* __restrict__ wu_lo)
{
    int tid = blockIdx.x * 256 + threadIdx.x;
    if (tid < DIN * DH) {                       // W_in [768][128]
        int k = tid >> 7, n = tid & 127;
        unsigned short h, l;
        split_bf(Wi[tid], h, l);
        int idx = ((k >> 5) * DH + n) * 32 + (k & 31);
        wi_hi[idx] = h; wi_lo[idx] = l;
    } else if (tid < DIN * DH + DH * G4) {      // W_up [128][512]
        int j = tid - DIN * DH;
        int k = j >> 9, n = j & 511;
        unsigned short h, l;
        split_bf(Wu[j], h, l);
        int idx = ((k >> 5) * G4 + n) * 32 + (k & 31);
        wu_hi[idx] = h; wu_lo[idx] = l;
    }
}

// ---------------------------------------------------------------------------
// Leaf: BM=128 rows/block (4 waves x 32 rows, M_rep=2), BN=128, BK=32.
// No LDS. x fp32 loaded 32B/lane/frag, split to hi/lo bf16 in registers.
// 3 MFMAs per product (hh, hl, lh) => ~2^-18 relative error.
// Epilogue: +bias, pair-average (register-local), write bf16 hi/lo planes.
// ---------------------------------------------------------------------------
__global__ __launch_bounds__(256, 2) void leaf_mfma(
    const float* __restrict__ x,
    const unsigned short* __restrict__ wi_hi, const unsigned short* __restrict__ wi_lo,
    const float* __restrict__ bin,
    unsigned short* __restrict__ h_hi, unsigned short* __restrict__ h_lo)
{
    const int t   = threadIdx.x;
    const int w   = t >> 6;        // wave 0..3 -> rows w*32..w*32+31
    const int l   = t & 63;
    const int l15 = l & 15, g = l >> 4;
    const size_t row0 = (size_t)blockIdx.x * 128;

    float4v acc[2][8];
#pragma unroll
    for (int mr = 0; mr < 2; ++mr)
#pragma unroll
        for (int nr = 0; nr < 8; ++nr) acc[mr][nr] = (float4v){0.f, 0.f, 0.f, 0.f};

    const float* xa0 = &x[(row0 + w * 32 + l15) * DIN + g * 8];
    const float* xa1 = xa0 + 16 * DIN;

    for (int s = 0; s < 24; ++s) {
        // A-fragments: 8 fp32 each, split to hi/lo bf16 in registers
        short8v ah[2], al[2];
#pragma unroll
        for (int mr = 0; mr < 2; ++mr) {
            const float* xp = (mr == 0 ? xa0 : xa1) + s * 32;
            const float4 va = *(const float4*)xp;
            const float4 vb = *(const float4*)(xp + 4);
            const float vv[8] = {va.x, va.y, va.z, va.w, vb.x, vb.y, vb.z, vb.w};
#pragma unroll
            for (int e = 0; e < 8; ++e) {
                unsigned short h_, l_;
                split_bf(vv[e], h_, l_);
                ah[mr][e] = (short)h_; al[mr][e] = (short)l_;
            }
        }
        const unsigned short* bh_t = wi_hi + (size_t)s * (DH * 32);
        const unsigned short* bl_t = wi_lo + (size_t)s * (DH * 32);
#pragma unroll
        for (int nr = 0; nr < 8; ++nr) {
            const int n = nr * 16 + l15;
            const short8v bh = *(const short8v*)&bh_t[n * 32 + g * 8];
            const short8v bl = *(const short8v*)&bl_t[n * 32 + g * 8];
#pragma unroll
            for (int mr = 0; mr < 2; ++mr) {
                acc[mr][nr] = __builtin_amdgcn_mfma_f32_16x16x32_bf16(ah[mr], bh, acc[mr][nr], 0, 0, 0);
                acc[mr][nr] = __builtin_amdgcn_mfma_f32_16x16x32_bf16(ah[mr], bl, acc[mr][nr], 0, 0, 0);
                acc[mr][nr] = __builtin_amdgcn_mfma_f32_16x16x32_bf16(al[mr], bh, acc[mr][nr], 0, 0, 0);
            }
        }
    }

    // epilogue: C/D rows = (lane>>4)*4 + reg (consecutive) -> pair-avg local
#pragma unroll
    for (int nr = 0; nr < 8; ++nr) {
        const int col = nr * 16 + l15;
        const float bv = bin[col];
#pragma unroll
        for (int mr = 0; mr < 2; ++mr) {
            const size_t obase = (row0 >> 1) + w * 16 + mr * 8 + g * 2;
#pragma unroll
            for (int j = 0; j < 2; ++j) {
                const float v = 0.5f * (acc[mr][nr][2 * j] + acc[mr][nr][2 * j + 1]) + bv;
                unsigned short h_, l_;
                split_bf(v, h_, l_);
                h_hi[(obase + j) * DH + col] = h_;
                h_lo[(obase + j) * DH + col] = l_;
            }
        }
    }
}

// ---------------------------------------------------------------------------
// One tree level. Block = 64 parents (4 waves x 16 parents); each wave owns
// ALL 512 gate cols (N_rep=32). i/o/u/f per (parent,d) are acc[n], acc[n+8],
// acc[n+16], acc[n+24] in the SAME lane. A and B direct from global.
// ---------------------------------------------------------------------------
template <bool HAS_C, bool LAST>
__global__ __launch_bounds__(256, 2) void level_mfma(
    const unsigned short* __restrict__ hin_hi, const unsigned short* __restrict__ hin_lo,
    const float* __restrict__ cin,
    const unsigned short* __restrict__ wu_hi, const unsigned short* __restrict__ wu_lo,
    const float* __restrict__ bu,
    unsigned short* __restrict__ hout_hi, unsigned short* __restrict__ hout_lo,
    float* __restrict__ cout, float* __restrict__ out, int P)
{
    const int t   = threadIdx.x;
    const int w   = t >> 6;
    const int l   = t & 63;
    const int l15 = l & 15, g = l >> 4;
    const int p0  = blockIdx.x * 64;
    const int prow = p0 + w * 16 + l15;     // A-operand row for this lane

    float4v acc[32];
#pragma unroll
    for (int nr = 0; nr < 32; ++nr) acc[nr] = (float4v){0.f, 0.f, 0.f, 0.f};

    const unsigned short* ah_p = &hin_hi[(size_t)prow * DH + g * 8];
    const unsigned short* al_p = &hin_lo[(size_t)prow * DH + g * 8];

    for (int s = 0; s < 4; ++s) {
        const short8v ah = *(const short8v*)(ah_p + s * 32);
        const short8v al = *(const short8v*)(al_p + s * 32);
        const unsigned short* bh_t = wu_hi + (size_t)s * (G4 * 32);
        const unsigned short* bl_t = wu_lo + (size_t)s * (G4 * 32);
#pragma unroll
        for (int nr = 0; nr < 32; ++nr) {
            const int n = nr * 16 + l15;
            const short8v bh = *(const short8v*)&bh_t[n * 32 + g * 8];
            const short8v bl = *(const short8v*)&bl_t[n * 32 + g * 8];
            acc[nr] = __builtin_amdgcn_mfma_f32_16x16x32_bf16(ah, bh, acc[nr], 0, 0, 0);
            acc[nr] = __builtin_amdgcn_mfma_f32_16x16x32_bf16(ah, bl, acc[nr], 0, 0, 0);
            acc[nr] = __builtin_amdgcn_mfma_f32_16x16x32_bf16(al, bh, acc[nr], 0, 0, 0);
        }
    }

    // epilogue: LSTM elementwise + pair-reduce, all register-local
#pragma unroll
    for (int n = 0; n < 8; ++n) {
        const int d = n * 16 + l15;
        const float bi_ = bu[d], bo_ = bu[128 + d], bu_ = bu[256 + d], bf_ = bu[384 + d];
        const float4v iv = acc[n], ov = acc[n + 8], uv = acc[n + 16], fv = acc[n + 24];
        float hr[4], cr[4];
#pragma unroll
        for (int r = 0; r < 4; ++r) {
            const int row = w * 16 + g * 4 + r;
            float csum = 0.f;
            if (HAS_C) csum = cin[(size_t)(p0 + row) * DH + d];
            const float ii = sigf(iv[r] + bi_);
            const float oo = sigf(ov[r] + bo_);
            const float uu = tanh_fast(uv[r] + bu_);
            const float ff = sigf(fv[r] + bf_);
            const float c = ii * uu + ff * csum;
            cr[r] = c;
            hr[r] = oo * tanh_fast(c);
        }
        if (LAST) {
#pragma unroll
            for (int r = 0; r < 4; ++r) {
                const int row = w * 16 + g * 4 + r;
                if (p0 + row < P) {
                    out[(size_t)(p0 + row) * DH + d] = hr[r];
                    out[1024 + (size_t)(p0 + row) * DH + d] = cr[r];
                }
            }
        } else {
#pragma unroll
            for (int j = 0; j < 2; ++j) {
                const int row2 = w * 16 + g * 4 + 2 * j;
                if (p0 + row2 < P) {
                    const size_t orow = (size_t)(p0 + row2) >> 1;
                    const float hv = 0.5f * (hr[2 * j] + hr[2 * j + 1]);
                    unsigned short h_, l_;
                    split_bf(hv, h_, l_);
                    hout_hi[orow * DH + d] = h_;
                    hout_lo[orow * DH + d] = l_;
                    cout[orow * DH + d] = cr[2 * j] + cr[2 * j + 1];
                }
            }
        }
    }
}

// ---------------------------------------------------------------------------
extern "C" void kernel_launch(void* const* d_in, const int* in_sizes, int n_in,
                              void* d_out, int out_size, void* d_ws, size_t ws_size,
                              hipStream_t stream)
{
    const float* x  = (const float*)d_in[0];
    const float* Wi = (const float*)d_in[1];
    const float* bi = (const float*)d_in[2];
    const float* Wu = (const float*)d_in[3];
    const float* bu = (const float*)d_in[4];
    float* out = (float*)d_out;

    char* ws = (char*)d_ws;
    const size_t MB = 1024 * 1024;
    // ws layout (ws_size is ~1.5GiB per r2 fill evidence; we use 66MB):
    //   [0,16M):   leaf h_hi / even-level h_hi (+lo,+c below)
    //   [16M,32M): leaf h_lo
    //   [32M,64M): odd-level outputs
    //   [64M,66M): split weights
    char* base_even = ws;
    char* base_odd  = ws + 32 * MB;
    char* wsplit    = ws + 64 * MB;

    unsigned short* wi_hi = (unsigned short*)wsplit;        // 768*128 each
    unsigned short* wi_lo = wi_hi + DIN * DH;
    unsigned short* wu_hi = wi_lo + DIN * DH;               // 128*512 each
    unsigned short* wu_lo = wu_hi + DH * G4;

    unsigned short* leaf_hi = (unsigned short*)ws;
    unsigned short* leaf_lo = (unsigned short*)(ws + 16 * MB);

    split_weights<<<(DIN * DH + DH * G4 + 255) / 256, 256, 0, stream>>>(
        Wi, Wu, wi_hi, wi_lo, wu_hi, wu_lo);

    // Leaf: 131072 rows, 128/block
    leaf_mfma<<<1024, 256, 0, stream>>>(x, wi_hi, wi_lo, bi, leaf_hi, leaf_lo);

    // 14 tree levels
    const unsigned short* ih = leaf_hi;
    const unsigned short* il = leaf_lo;
    const float* ic = nullptr;
    int P = 65536;
    for (int lvl = 1; lvl <= 14; ++lvl) {
        const int P2 = P >> 1;
        char* base = (lvl & 1) ? base_odd : base_even;
        unsigned short* oh = (unsigned short*)base;
        unsigned short* ol = (unsigned short*)(base + (size_t)P2 * 256);
        float* oc = (float*)(base + (size_t)P2 * 512);
        const int grid = (P + 63) / 64;
        if (lvl == 1)
            level_mfma<false, false><<<grid, 256, 0, stream>>>(
                ih, il, nullptr, wu_hi, wu_lo, bu, oh, ol, oc, nullptr, P);
        else if (lvl < 14)
            level_mfma<true, false><<<grid, 256, 0, stream>>>(
                ih, il, ic, wu_hi, wu_lo, bu, oh, ol, oc, nullptr, P);
        else
            level_mfma<true, true><<<grid, 256, 0, stream>>>(
                ih, il, ic, wu_hi, wu_lo, bu, nullptr, nullptr, nullptr, out, P);
        ih = oh; il = ol; ic = oc; P = P2;
    }
}

// Round 4
// 1043.866 us; speedup vs baseline: 1.1740x; 1.1740x over previous
//
#include <hip/hip_runtime.h>
#include <math.h>

// ChildSumTreeLSTM — bf16 split-precision MFMA, round 4.
//  * Leaf: x direct->reg, W_in hi/lo staged in LDS via global_load_lds,
//    double-buffered, conflict-free [g][n][8] tiling.
//  * Tree: 4 level-kernels total. Fused subtree kernels keep inter-level
//    h/c in LDS (f32, ping-pong halves), W_up staged per level from L2.
//  * 3-MFMA split (hh, hl, lh) => ~2^-18 rel err, matches fp32 reference.

#define DIN 768
#define DH  128
#define G4  512

typedef unsigned short ushort_t;
typedef __attribute__((ext_vector_type(8))) short short8v;
typedef __attribute__((ext_vector_type(4))) float float4v;

__device__ __forceinline__ ushort_t bf16_rne(float v) {
    unsigned u = __float_as_uint(v);
    return (ushort_t)((u + 0x7FFFu + ((u >> 16) & 1u)) >> 16);
}
__device__ __forceinline__ float bf16_to_f(ushort_t h) {
    return __uint_as_float(((unsigned)h) << 16);
}
__device__ __forceinline__ void split_bf(float v, ushort_t& hi, ushort_t& lo) {
    hi = bf16_rne(v);
    lo = bf16_rne(v - bf16_to_f(hi));
}
__device__ __forceinline__ float sigf(float x) { return 1.0f / (1.0f + __expf(-x)); }
__device__ __forceinline__ float tanh_fast(float x) {
    return 1.0f - 2.0f / (1.0f + __expf(2.0f * x));
}

// global->LDS DMA, 16B per lane; lds dest must be wave-uniform base.
#define GLD16(gp, lp)                                                          \
    __builtin_amdgcn_global_load_lds(                                          \
        (const __attribute__((address_space(1))) void*)(gp),                   \
        (__attribute__((address_space(3))) void*)(lp), 16, 0, 0)

// ---------------------------------------------------------------------------
// Weight pre-tiling: element (k = s*32+g*8+e, n) -> ((s*4+g)*N + n)*8 + e.
// A wave's B-fragment (16 n x 8 e at fixed g) is contiguous; LDS reads are
// 2-way-conflict max (free).
// ---------------------------------------------------------------------------
__global__ __launch_bounds__(256) void split_weights(
    const float* __restrict__ Wi, const float* __restrict__ Wu,
    ushort_t* __restrict__ wi_hi, ushort_t* __restrict__ wi_lo,
    ushort_t* __restrict__ wu_hi, ushort_t* __restrict__ wu_lo)
{
    int tid = blockIdx.x * 256 + threadIdx.x;
    if (tid < DIN * DH) {                       // W_in [768][128]
        int k = tid >> 7, n = tid & 127;
        int s = k >> 5, g = (k >> 3) & 3, e = k & 7;
        ushort_t h, l;
        split_bf(Wi[tid], h, l);
        int idx = ((s * 4 + g) * DH + n) * 8 + e;
        wi_hi[idx] = h; wi_lo[idx] = l;
    } else if (tid < DIN * DH + DH * G4) {      // W_up [128][512]
        int j = tid - DIN * DH;
        int k = j >> 9, n = j & 511;
        int s = k >> 5, g = (k >> 3) & 3, e = k & 7;
        ushort_t h, l;
        split_bf(Wu[j], h, l);
        int idx = ((s * 4 + g) * G4 + n) * 8 + e;
        wu_hi[idx] = h; wu_lo[idx] = l;
    }
}

// ---------------------------------------------------------------------------
// Leaf: BM=128 (4 waves x 32 rows, M_rep=2), BN=128, BK=32, 24 K-steps.
// ---------------------------------------------------------------------------
__global__ __launch_bounds__(256, 2) void leaf_mfma(
    const float* __restrict__ x,
    const ushort_t* __restrict__ wi_hi, const ushort_t* __restrict__ wi_lo,
    const float* __restrict__ bin,
    ushort_t* __restrict__ h_hi, ushort_t* __restrict__ h_lo)
{
    __shared__ __align__(16) ushort_t Wh[2][4096], Wl[2][4096];

    const int t = threadIdx.x, w = t >> 6, lane = t & 63;
    const int l15 = lane & 15, g = lane >> 4;
    const size_t row0 = (size_t)blockIdx.x * 128;

    float4v acc[2][8];
#pragma unroll
    for (int mr = 0; mr < 2; ++mr)
#pragma unroll
        for (int nr = 0; nr < 8; ++nr) acc[mr][nr] = (float4v){0.f, 0.f, 0.f, 0.f};

    const float* xr0 = &x[(row0 + w * 32 + l15) * DIN + g * 8];
    const float* xr1 = xr0 + 16 * DIN;

    // stage tile s into buffer b
#define LEAF_STAGE(s, b)                                                       \
    {                                                                          \
        _Pragma("unroll") for (int i = 0; i < 2; ++i) {                        \
            GLD16(wi_hi + (s) * 4096 + i * 2048 + t * 8,                       \
                  &Wh[b][i * 2048 + w * 512]);                                 \
            GLD16(wi_lo + (s) * 4096 + i * 2048 + t * 8,                       \
                  &Wl[b][i * 2048 + w * 512]);                                 \
        }                                                                      \
    }

    float4 xc[4];
    xc[0] = *(const float4*)(xr0);
    xc[1] = *(const float4*)(xr0 + 4);
    xc[2] = *(const float4*)(xr1);
    xc[3] = *(const float4*)(xr1 + 4);
    LEAF_STAGE(0, 0);

    for (int s = 0; s < 24; ++s) {
        __syncthreads();            // drains DMA of tile s + x prefetch
        float4 xn[4];
        if (s < 23) {
            LEAF_STAGE(s + 1, (s + 1) & 1);
            const float* a0 = xr0 + (s + 1) * 32;
            const float* a1 = xr1 + (s + 1) * 32;
            xn[0] = *(const float4*)(a0);
            xn[1] = *(const float4*)(a0 + 4);
            xn[2] = *(const float4*)(a1);
            xn[3] = *(const float4*)(a1 + 4);
        }
        // A fragments from xc
        short8v ah[2], al[2];
#pragma unroll
        for (int mr = 0; mr < 2; ++mr) {
            const float vv[8] = {xc[2*mr].x, xc[2*mr].y, xc[2*mr].z, xc[2*mr].w,
                                 xc[2*mr+1].x, xc[2*mr+1].y, xc[2*mr+1].z, xc[2*mr+1].w};
#pragma unroll
            for (int e = 0; e < 8; ++e) {
                ushort_t h_, l_;
                split_bf(vv[e], h_, l_);
                ah[mr][e] = (short)h_; al[mr][e] = (short)l_;
            }
        }
        const int b = s & 1;
#pragma unroll
        for (int nr = 0; nr < 8; ++nr) {
            const int n = nr * 16 + l15;
            const short8v bh = *(const short8v*)&Wh[b][(g * DH + n) * 8];
            const short8v bl = *(const short8v*)&Wl[b][(g * DH + n) * 8];
#pragma unroll
            for (int mr = 0; mr < 2; ++mr) {
                acc[mr][nr] = __builtin_amdgcn_mfma_f32_16x16x32_bf16(ah[mr], bh, acc[mr][nr], 0, 0, 0);
                acc[mr][nr] = __builtin_amdgcn_mfma_f32_16x16x32_bf16(ah[mr], bl, acc[mr][nr], 0, 0, 0);
                acc[mr][nr] = __builtin_amdgcn_mfma_f32_16x16x32_bf16(al[mr], bh, acc[mr][nr], 0, 0, 0);
            }
        }
#pragma unroll
        for (int q = 0; q < 4; ++q) xc[q] = xn[q];
    }

    // epilogue: +bias, pair-average (C/D rows consecutive), split, store
#pragma unroll
    for (int nr = 0; nr < 8; ++nr) {
        const int col = nr * 16 + l15;
        const float bv = bin[col];
#pragma unroll
        for (int mr = 0; mr < 2; ++mr) {
            const size_t obase = (row0 >> 1) + w * 16 + mr * 8 + g * 2;
#pragma unroll
            for (int j = 0; j < 2; ++j) {
                const float v = 0.5f * (acc[mr][nr][2 * j] + acc[mr][nr][2 * j + 1]) + bv;
                ushort_t h_, l_;
                split_bf(v, h_, l_);
                h_hi[(obase + j) * DH + col] = h_;
                h_lo[(obase + j) * DH + col] = l_;
            }
        }
    }
#undef LEAF_STAGE
}

// ---------------------------------------------------------------------------
// Fused tree levels. Block = 64 parents at entry level; NLEV levels fused.
// Wave w owns 16 parents x all 512 gate cols (i/o/u/f in same lane's acc).
// Inter-level h/c in LDS f32 (row stride 129, ping-pong halves 0/32).
// ---------------------------------------------------------------------------
template <int NLEV, bool IN_RAW, bool HAS_C, bool FINAL>
__global__ __launch_bounds__(256, 1) void tree_levels(
    const ushort_t* __restrict__ hin_hi, const ushort_t* __restrict__ hin_lo,
    const float* __restrict__ cin,
    const ushort_t* __restrict__ wuh, const ushort_t* __restrict__ wul,
    const float* __restrict__ bu,
    ushort_t* __restrict__ hout_hi, ushort_t* __restrict__ hout_lo,
    float* __restrict__ cout, float* __restrict__ out)
{
    __shared__ __align__(16) ushort_t Wh[16384], Wl[16384];   // 32KB + 32KB
    constexpr int HROWS = (NLEV > 1) ? 48 : 1;
    __shared__ float hbuf[HROWS * 129], cbuf[HROWS * 129];

    const int t = threadIdx.x, w = t >> 6, lane = t & 63;
    const int l15 = lane & 15, g = lane >> 4;
    const int p0 = blockIdx.x * 64;
    const int prow = w * 16 + l15;

    // hoist biases: d = n*16 + l15
    float bia[8], bio[8], biu[8], bif[8];
#pragma unroll
    for (int n = 0; n < 8; ++n) {
        const int d = n * 16 + l15;
        bia[n] = bu[d]; bio[n] = bu[128 + d];
        biu[n] = bu[256 + d]; bif[n] = bu[384 + d];
    }

    for (int lev = 0; lev < NLEV; ++lev) {
        const int Pb = 64 >> lev;                 // parents in block
        const int nw = (Pb >= 16) ? (Pb >> 4) : 1;
        const int inb  = ((lev - 1) & 1) ? 32 : 0;  // where lev-1 wrote
        const int outb = (lev & 1) ? 32 : 0;

        float4v acc[32];
#pragma unroll
        for (int nr = 0; nr < 32; ++nr) acc[nr] = (float4v){0.f, 0.f, 0.f, 0.f};

        for (int s = 0; s < 4; ++s) {
            // stage W tile s (64KB, shared by block)
#pragma unroll
            for (int i = 0; i < 8; ++i) {
                GLD16(wuh + s * 16384 + i * 2048 + t * 8, &Wh[i * 2048 + w * 512]);
                GLD16(wul + s * 16384 + i * 2048 + t * 8, &Wl[i * 2048 + w * 512]);
            }
            // A fragment (parallel with DMA)
            short8v ah{}, al{};
            if (w < nw) {
                if (lev == 0) {
                    if (IN_RAW) {
                        const size_t r2 = (size_t)(2 * (p0 + prow)) * DH + s * 32 + g * 8;
                        const short8v h0 = *(const short8v*)&hin_hi[r2];
                        const short8v l0 = *(const short8v*)&hin_lo[r2];
                        const short8v h1 = *(const short8v*)&hin_hi[r2 + DH];
                        const short8v l1 = *(const short8v*)&hin_lo[r2 + DH];
#pragma unroll
                        for (int e = 0; e < 8; ++e) {
                            const float v = 0.5f * ((bf16_to_f((ushort_t)h0[e]) + bf16_to_f((ushort_t)l0[e])) +
                                                    (bf16_to_f((ushort_t)h1[e]) + bf16_to_f((ushort_t)l1[e])));
                            ushort_t h_, l_;
                            split_bf(v, h_, l_);
                            ah[e] = (short)h_; al[e] = (short)l_;
                        }
                    } else {
                        const size_t r = (size_t)(p0 + prow) * DH + s * 32 + g * 8;
                        ah = *(const short8v*)&hin_hi[r];
                        al = *(const short8v*)&hin_lo[r];
                    }
                } else {
#pragma unroll
                    for (int e = 0; e < 8; ++e) {
                        const float v = hbuf[(inb + prow) * 129 + s * 32 + g * 8 + e];
                        ushort_t h_, l_;
                        split_bf(v, h_, l_);
                        ah[e] = (short)h_; al[e] = (short)l_;
                    }
                }
            }
            __syncthreads();        // W tile ready (vmcnt drained)
            if (w < nw) {
#pragma unroll
                for (int nr = 0; nr < 32; ++nr) {
                    const int n = nr * 16 + l15;
                    const short8v bh = *(const short8v*)&Wh[(g * G4 + n) * 8];
                    const short8v bl = *(const short8v*)&Wl[(g * G4 + n) * 8];
                    acc[nr] = __builtin_amdgcn_mfma_f32_16x16x32_bf16(ah, bh, acc[nr], 0, 0, 0);
                    acc[nr] = __builtin_amdgcn_mfma_f32_16x16x32_bf16(ah, bl, acc[nr], 0, 0, 0);
                    acc[nr] = __builtin_amdgcn_mfma_f32_16x16x32_bf16(al, bh, acc[nr], 0, 0, 0);
                }
            }
            __syncthreads();        // drain W reads before next stage
        }

        // ---- epilogue -----------------------------------------------------
        if (w < nw) {
#pragma unroll
            for (int n = 0; n < 8; ++n) {
                const int d = n * 16 + l15;
                float hr[4], cr[4];
#pragma unroll
                for (int r = 0; r < 4; ++r) {
                    const int row = w * 16 + g * 4 + r;
                    float csum = 0.f;
                    if (HAS_C || lev > 0) {
                        if (lev == 0) {
                            if (IN_RAW)
                                csum = cin[(size_t)(2 * (p0 + row)) * DH + d] +
                                       cin[(size_t)(2 * (p0 + row) + 1) * DH + d];
                            else
                                csum = cin[(size_t)(p0 + row) * DH + d];
                        } else {
                            csum = cbuf[(inb + row) * 129 + d];
                        }
                    }
                    const float ii = sigf(acc[n][r] + bia[n]);
                    const float oo = sigf(acc[n + 8][r] + bio[n]);
                    const float uu = tanh_fast(acc[n + 16][r] + biu[n]);
                    const float ff = sigf(acc[n + 24][r] + bif[n]);
                    const float c = ii * uu + ff * csum;
                    cr[r] = c;
                    hr[r] = oo * tanh_fast(c);
                }
                if (lev == NLEV - 1) {
                    if (FINAL) {
                        // roots: 64>>(NLEV-1) per block
#pragma unroll
                        for (int r = 0; r < 4; ++r) {
                            const int row = w * 16 + g * 4 + r;
                            if (row < Pb) {
                                const int root = blockIdx.x * Pb + row;
                                out[(size_t)root * DH + d] = hr[r];
                                out[1024 + (size_t)root * DH + d] = cr[r];
                            }
                        }
                    } else if (Pb == 1) {
                        // raw single node out
                        if (g == 0) {   // row 0 lives in g==0, r==0
                            const int node = blockIdx.x;
                            ushort_t h_, l_;
                            split_bf(hr[0], h_, l_);
                            hout_hi[(size_t)node * DH + d] = h_;
                            hout_lo[(size_t)node * DH + d] = l_;
                            cout[(size_t)node * DH + d] = cr[0];
                        }
                    } else {
                        // pair-averaged global out (NLEV==1 kernels)
#pragma unroll
                        for (int j = 0; j < 2; ++j) {
                            const int row2 = w * 16 + g * 4 + 2 * j;
                            if (row2 < Pb) {
                                const size_t orow = (size_t)(p0 + row2) >> 1;
                                const float hv = 0.5f * (hr[2 * j] + hr[2 * j + 1]);
                                ushort_t h_, l_;
                                split_bf(hv, h_, l_);
                                hout_hi[orow * DH + d] = h_;
                                hout_lo[orow * DH + d] = l_;
                                cout[orow * DH + d] = cr[2 * j] + cr[2 * j + 1];
                            }
                        }
                    }
                } else {
                    // pair-avg into LDS for next level
#pragma unroll
                    for (int j = 0; j < 2; ++j) {
                        const int row2 = w * 16 + g * 4 + 2 * j;
                        if (row2 < Pb) {
                            const int orow = outb + (row2 >> 1);
                            hbuf[orow * 129 + d] = 0.5f * (hr[2 * j] + hr[2 * j + 1]);
                            cbuf[orow * 129 + d] = cr[2 * j] + cr[2 * j + 1];
                        }
                    }
                }
            }
        }
        __syncthreads();            // publish LDS h/c for next level
    }
}

// ---------------------------------------------------------------------------
extern "C" void kernel_launch(void* const* d_in, const int* in_sizes, int n_in,
                              void* d_out, int out_size, void* d_ws, size_t ws_size,
                              hipStream_t stream)
{
    const float* x  = (const float*)d_in[0];
    const float* Wi = (const float*)d_in[1];
    const float* bi = (const float*)d_in[2];
    const float* Wu = (const float*)d_in[3];
    const float* bu = (const float*)d_in[4];
    float* out = (float*)d_out;

    char* ws = (char*)d_ws;
    const size_t MB = 1024 * 1024;

    ushort_t* leafH = (ushort_t*)(ws);             // 65536x128 bf16 = 16MB
    ushort_t* leafL = (ushort_t*)(ws + 16 * MB);
    ushort_t* l1H   = (ushort_t*)(ws + 32 * MB);   // 32768 rows = 8MB
    ushort_t* l1L   = (ushort_t*)(ws + 40 * MB);
    float*    l1C   = (float*)   (ws + 48 * MB);   // 16MB
    ushort_t* l2H   = (ushort_t*)(ws + 64 * MB);   // 16384 rows = 4MB
    ushort_t* l2L   = (ushort_t*)(ws + 68 * MB);
    float*    l2C   = (float*)   (ws + 72 * MB);   // 8MB
    ushort_t* s9H   = (ushort_t*)(ws + 80 * MB);   // 256 rows = 64KB
    ushort_t* s9L   = (ushort_t*)(ws + 80 * MB + 65536);
    float*    s9C   = (float*)   (ws + 80 * MB + 131072);
    ushort_t* wiH   = (ushort_t*)(ws + 81 * MB);
    ushort_t* wiL   = wiH + DIN * DH;
    ushort_t* wuH   = wiL + DIN * DH;
    ushort_t* wuL   = wuH + DH * G4;

    split_weights<<<(DIN * DH + DH * G4 + 255) / 256, 256, 0, stream>>>(
        Wi, Wu, wiH, wiL, wuH, wuL);

    leaf_mfma<<<1024, 256, 0, stream>>>(x, wiH, wiL, bi, leafH, leafL);

    // level 1 (P=65536), level 2 (P=32768)
    tree_levels<1, false, false, false><<<1024, 256, 0, stream>>>(
        leafH, leafL, nullptr, wuH, wuL, bu, l1H, l1L, l1C, nullptr);
    tree_levels<1, false, true, false><<<512, 256, 0, stream>>>(
        l1H, l1L, l1C, wuH, wuL, bu, l2H, l2L, l2C, nullptr);
    // levels 3..9 fused (P3=16384 -> raw level-9 nodes)
    tree_levels<7, false, true, false><<<256, 256, 0, stream>>>(
        l2H, l2L, l2C, wuH, wuL, bu, s9H, s9L, s9C, nullptr);
    // levels 10..14 fused (raw in, final out)
    tree_levels<5, true, true, true><<<2, 256, 0, stream>>>(
        s9H, s9L, s9C, wuH, wuL, bu, nullptr, nullptr, nullptr, out);
}